// Round 3
// baseline (399.947 us; speedup 1.0000x reference)
//
#include <hip/hip_runtime.h>

typedef unsigned short ushort_t;
typedef unsigned int uint_t;
typedef short bf16x8 __attribute__((ext_vector_type(8)));
typedef float f32x4 __attribute__((ext_vector_type(4)));

#define MFMA16(a, b, c) __builtin_amdgcn_mfma_f32_16x16x32_bf16((a), (b), (c), 0, 0, 0)

// ---------- numeric helpers ----------
__device__ __forceinline__ ushort_t f2bf(float f) {
  uint_t u = __float_as_uint(f);
  u += 0x7fffu + ((u >> 16) & 1u);   // RNE; inputs finite
  return (ushort_t)(u >> 16);
}
__device__ __forceinline__ float bf2f(ushort_t h) {
  return __uint_as_float(((uint_t)h) << 16);
}
__device__ __forceinline__ float eluf(float x) {
  float e = __expf(x) - 1.0f;
  return x > 0.0f ? x : e;
}
__device__ __forceinline__ float sigmf(float x) {
  return 1.0f / (1.0f + __expf(-x));
}

// ---------- sizes / workspace layout (ushort elements) ----------
constexpr int BSK = 32768;           // 2048 * 16 objects
constexpr size_t OFF_ENCF = 0;       // enc_flat bf16 [32768][128]
constexpr size_t OFF_ENC  = 4194304; // enc bf16 [32768][128]
constexpr size_t OFF_TEFF = 8388608; // total_effect bf16 [32768][64]
constexpr size_t OFF_FR   = 10485760;

// fragment-layout weight offsets (ushort elements, relative to OFF_FR)
constexpr int FR_LE_W1  = 0;        // 128x128
constexpr int FR_LE_W2  = 16384;    // 128x128
constexpr int FR_AE_W2  = 32768;    // 128x64
constexpr int FR_AEF_W1 = 40960;    // 192x128
constexpr int FR_AAT_W1 = 65536;    // 192x128
constexpr int FR_AEF_W2 = 90112;    // 128x128
constexpr int FR_PE_W1  = 106496;   // 256x256
constexpr int FR_PE_W2  = 172032;   // 256x128
constexpr int FR_IE_W1  = 204800;   // 128x128
constexpr int FR_IE_W2  = 221184;   // 128x64
constexpr int FR_IA_W1  = 229376;   // 128x128
constexpr int FR_FM_W1  = 245760;   // 192x128
constexpr int FR_FM_W2  = 270336;   // 128x128

// ---------- weight prep: fp32 (K,N) row-major -> bf16 MFMA B-fragments ----------
// frag f = ntile*(K/32) + kstep; element idx = f*512 + lane*8 + e
// holds W[kstep*32 + (lane>>4)*8 + e][ntile*16 + (lane&15)]
struct PrepDesc { const float* src; ushort_t* dst; int K; int N; };
struct PrepArgs { PrepDesc d[13]; };

__global__ __launch_bounds__(256) void prep_kernel(PrepArgs a) {
  PrepDesc p = a.d[blockIdx.y];
  int idx = blockIdx.x * 256 + threadIdx.x;
  if (idx >= p.K * p.N) return;
  int e = idx & 7;
  int lane = (idx >> 3) & 63;
  int f = idx >> 9;
  int ksteps = p.K >> 5;
  int kstep = f % ksteps;
  int ntile = f / ksteps;
  int k = kstep * 32 + ((lane >> 4) << 3) + e;
  int n = ntile * 16 + (lane & 15);
  p.dst[idx] = f2bf(p.src[k * p.N + n]);
}

// ---------- GEMM building blocks ----------
// A-frag: lane holds A[row = lane&15][k = ks*32 + (lane>>4)*8 + e]
// B-frag: lane holds W[k][col = ntile*16 + (lane&15)]  (from prep buffer)
// D: lane holds D[row = (lane>>4)*4 + r][col = lane&15]
// LDS tiles are row-major bf16 with byte-XOR swizzle colb ^= (row&7)<<4.

template <int MT, int NT, int KS>
__device__ __forceinline__ void reg_gemm(const bf16x8 a[MT][KS],
                                         const ushort_t* __restrict__ wfrag,
                                         int ntile0, int lane, f32x4 acc[MT][NT]) {
  const f32x4 z = {0.f, 0.f, 0.f, 0.f};
#pragma unroll
  for (int nt = 0; nt < NT; ++nt) {
#pragma unroll
    for (int m = 0; m < MT; ++m) acc[m][nt] = z;
    const ushort_t* wf = wfrag + (size_t)((ntile0 + nt) * KS) * 512 + lane * 8;
#pragma unroll
    for (int ks = 0; ks < KS; ++ks) {
      bf16x8 bfr = *(const bf16x8*)(wf + ks * 512);
#pragma unroll
      for (int m = 0; m < MT; ++m) acc[m][nt] = MFMA16(a[m][ks], bfr, acc[m][nt]);
    }
  }
}

template <int MT, int NT, int KS>
__device__ __forceinline__ void lds_gemm(const ushort_t* __restrict__ Abase,
                                         const ushort_t* __restrict__ wfrag,
                                         int ntile0, int lane, f32x4 acc[MT][NT]) {
  const int r = lane & 15, q = lane >> 4;
  const int swz = (r & 7) << 4;
  bf16x8 a[MT][KS];
#pragma unroll
  for (int m = 0; m < MT; ++m)
#pragma unroll
    for (int ks = 0; ks < KS; ++ks) {
      int row = m * 16 + r;
      int colb = (ks * 64 + q * 16) ^ swz;
      a[m][ks] = *(const bf16x8*)((const char*)Abase + row * (KS * 64) + colb);
    }
  reg_gemm<MT, NT, KS>(a, wfrag, ntile0, lane, acc);
}

template <int MT, int NT, bool ELU>
__device__ __forceinline__ void add_bias_act(f32x4 acc[MT][NT], const float* __restrict__ bias,
                                             int col0, int lane) {
  const int r = lane & 15;
#pragma unroll
  for (int nt = 0; nt < NT; ++nt) {
    float bv = bias[col0 + nt * 16 + r];
#pragma unroll
    for (int m = 0; m < MT; ++m)
#pragma unroll
      for (int k = 0; k < 4; ++k) {
        float v = acc[m][nt][k] + bv;
        acc[m][nt][k] = ELU ? eluf(v) : v;
      }
  }
}

template <int MT, int NT, int CCB>  // CCB = LDS row stride in bytes
__device__ __forceinline__ void store_lds(ushort_t* Dbase, int col0, int lane,
                                          const f32x4 acc[MT][NT]) {
  const int cr = lane & 15, cq = lane >> 4;
#pragma unroll
  for (int m = 0; m < MT; ++m)
#pragma unroll
    for (int nt = 0; nt < NT; ++nt)
#pragma unroll
      for (int k = 0; k < 4; ++k) {
        int row = m * 16 + cq * 4 + k;
        int colb = ((col0 + nt * 16 + cr) * 2) ^ ((row & 7) << 4);
        *(ushort_t*)((char*)Dbase + row * CCB + colb) = f2bf(acc[m][nt][k]);
      }
}

template <int MT, int NT>
__device__ __forceinline__ void store_global(ushort_t* __restrict__ G, int row0, int ncols,
                                             int col0, int lane, const f32x4 acc[MT][NT]) {
  const int cr = lane & 15, cq = lane >> 4;
#pragma unroll
  for (int m = 0; m < MT; ++m)
#pragma unroll
    for (int nt = 0; nt < NT; ++nt)
#pragma unroll
      for (int k = 0; k < 4; ++k) {
        int row = m * 16 + cq * 4 + k;
        G[(size_t)(row0 + row) * ncols + col0 + nt * 16 + cr] = f2bf(acc[m][nt][k]);
      }
}

template <int MT, int NT>
__device__ __forceinline__ void store_global_f32(float* __restrict__ G, int row0, int ncols,
                                                 int col0, int lane, const f32x4 acc[MT][NT]) {
  const int cr = lane & 15, cq = lane >> 4;
#pragma unroll
  for (int m = 0; m < MT; ++m)
#pragma unroll
    for (int nt = 0; nt < NT; ++nt)
#pragma unroll
      for (int k = 0; k < 4; ++k) {
        int row = m * 16 + cq * 4 + k;
        G[(size_t)(row0 + row) * ncols + col0 + nt * 16 + cr] = acc[m][nt][k];
      }
}

// ---------- kernel 1: per-object encoder (le, ae, aef, aat -> enc_flat, enc) ----------
__global__ __launch_bounds__(256, 2) void enc_kernel(
    const float* __restrict__ lambda1, const float* __restrict__ actions,
    const float* __restrict__ le_b1, const float* __restrict__ le_b2,
    const float* __restrict__ ae_W1, const float* __restrict__ ae_b1,
    const float* __restrict__ ae_b2, const float* __restrict__ aef_b1,
    const float* __restrict__ aef_b2, const float* __restrict__ aat_b1,
    const float* __restrict__ aat_W2, const float* __restrict__ aat_b2,
    const ushort_t* __restrict__ fr, ushort_t* __restrict__ encf, ushort_t* __restrict__ enc) {
  __shared__ ushort_t bufA[64 * 128];  // 16 KB
  __shared__ ushort_t bufB[64 * 128];  // 16 KB
  __shared__ ushort_t la[64 * 192];    // 24 KB
  __shared__ float att[64];

  const int t = threadIdx.x, lane = t & 63, w = t >> 6;
  const int rows0 = blockIdx.x * 64;

  // stage lambda1 tile -> bufA (bf16, swizzled)
  {
    const int row = t >> 2, c0 = (t & 3) * 32;
    const float4* src = (const float4*)(lambda1 + (size_t)(rows0 + row) * 128 + c0);
    const int swz = (row & 7) << 4;
#pragma unroll
    for (int j = 0; j < 8; ++j) {
      float4 v = src[j];
      uint2 p;
      p.x = (uint_t)f2bf(v.x) | ((uint_t)f2bf(v.y) << 16);
      p.y = (uint_t)f2bf(v.z) | ((uint_t)f2bf(v.w) << 16);
      int colb = ((c0 + j * 4) * 2) ^ swz;
      *(uint2*)((char*)bufA + row * 256 + colb) = p;
    }
  }
  __syncthreads();

  f32x4 acc2[4][2];
  // le layer 1: bufA -> bufB
  lds_gemm<4, 2, 4>(bufA, fr + FR_LE_W1, w * 2, lane, acc2);
  add_bias_act<4, 2, true>(acc2, le_b1, w * 32, lane);
  store_lds<4, 2, 256>(bufB, w * 32, lane, acc2);
  __syncthreads();
  // le layer 2: bufB -> la[:,0:128] + global enc_flat
  lds_gemm<4, 2, 4>(bufB, fr + FR_LE_W2, w * 2, lane, acc2);
  add_bias_act<4, 2, true>(acc2, le_b2, w * 32, lane);
  store_lds<4, 2, 384>(la, w * 32, lane, acc2);
  store_global<4, 2>(encf, rows0, 128, w * 32, lane, acc2);
  // ae layer 1 (K=6, VALU) : actions -> bufA (bufA free after prior sync)
  {
    const int row = t >> 2, c0 = (t & 3) * 32;
    float a6[6];
#pragma unroll
    for (int k2 = 0; k2 < 6; ++k2) a6[k2] = actions[(size_t)(rows0 + row) * 6 + k2];
    const int swz = (row & 7) << 4;
#pragma unroll
    for (int j = 0; j < 16; ++j) {
      int c = c0 + j * 2;
      float s0 = ae_b1[c], s1 = ae_b1[c + 1];
#pragma unroll
      for (int k2 = 0; k2 < 6; ++k2) {
        s0 += a6[k2] * ae_W1[k2 * 128 + c];
        s1 += a6[k2] * ae_W1[k2 * 128 + c + 1];
      }
      uint_t pp = (uint_t)f2bf(eluf(s0)) | ((uint_t)f2bf(eluf(s1)) << 16);
      *(uint_t*)((char*)bufA + row * 256 + ((c * 2) ^ swz)) = pp;
    }
  }
  __syncthreads();
  // ae layer 2: bufA -> la[:,128:192]
  {
    f32x4 acc1[4][1];
    lds_gemm<4, 1, 4>(bufA, fr + FR_AE_W2, w, lane, acc1);
    add_bias_act<4, 1, true>(acc1, ae_b2, w * 16, lane);
    store_lds<4, 1, 384>(la, 128 + w * 16, lane, acc1);
  }
  __syncthreads();
  // aef layer 1: la -> bufA ; aat layer 1: la -> bufB
  lds_gemm<4, 2, 6>(la, fr + FR_AEF_W1, w * 2, lane, acc2);
  add_bias_act<4, 2, true>(acc2, aef_b1, w * 32, lane);
  store_lds<4, 2, 256>(bufA, w * 32, lane, acc2);
  lds_gemm<4, 2, 6>(la, fr + FR_AAT_W1, w * 2, lane, acc2);
  add_bias_act<4, 2, true>(acc2, aat_b1, w * 32, lane);
  store_lds<4, 2, 256>(bufB, w * 32, lane, acc2);
  __syncthreads();
  // aef layer 2: bufA -> regs (a_eff)
  lds_gemm<4, 2, 4>(bufA, fr + FR_AEF_W2, w * 2, lane, acc2);
  add_bias_act<4, 2, true>(acc2, aef_b2, w * 32, lane);
  // aat layer 2 (N=1, VALU): bufB -> att
  {
    const int row = t >> 2, s = t & 3;
    const int swz = (row & 7) << 4;
    float sum = 0.f;
#pragma unroll
    for (int j = 0; j < 32; ++j) {
      int c = s * 32 + j;
      sum += bf2f(*(const ushort_t*)((const char*)bufB + row * 256 + ((c * 2) ^ swz))) * aat_W2[c];
    }
    sum += __shfl_xor(sum, 1);
    sum += __shfl_xor(sum, 2);
    if (s == 0) att[row] = sigmf(sum + aat_b2[0]);
  }
  __syncthreads();
  // enc = a_eff * a_att -> global
  {
    const int cr = lane & 15, cq = lane >> 4;
#pragma unroll
    for (int m = 0; m < 4; ++m)
#pragma unroll
      for (int nt = 0; nt < 2; ++nt)
#pragma unroll
        for (int k = 0; k < 4; ++k) {
          int row = m * 16 + cq * 4 + k;
          enc[(size_t)(rows0 + row) * 128 + w * 32 + nt * 16 + cr] =
              f2bf(acc2[m][nt][k] * att[row]);
        }
  }
}

// ---------- kernel 2: pairwise stage (pe, ie, ia, attention-weighted sum over j) ----------
// Block = 2 groups (b,i), M = 32 rows = all 16 j's per group (j==i masked in reduce).
__global__ __launch_bounds__(256, 3) void pair_kernel(
    const ushort_t* __restrict__ enc, const ushort_t* __restrict__ fr,
    const float* __restrict__ pe_b1, const float* __restrict__ pe_b2,
    const float* __restrict__ ie_b1, const float* __restrict__ ie_b2,
    const float* __restrict__ ia_b1, const float* __restrict__ ia_W2,
    const float* __restrict__ ia_b2, ushort_t* __restrict__ teff) {
  __shared__ ushort_t bufH[32 * 256];   // 16 KB (h_pe; later h_ie | h_ia)
  __shared__ ushort_t bufPi[32 * 128];  // 8 KB
  __shared__ float att[32];

  const int t = threadIdx.x, lane = t & 63, w = t >> 6;
  const int r = lane & 15, q = lane >> 4;
  const int g0 = blockIdx.x * 2;
  const int b = g0 >> 4;

  // pe layer-1 A-fragments straight from global enc (held in regs for whole K-loop)
  bf16x8 a[2][8];
#pragma unroll
  for (int m = 0; m < 2; ++m) {
    const int im = (g0 + m) & 15;
#pragma unroll
    for (int ks = 0; ks < 8; ++ks) {
      const int srow = (ks < 4) ? im : r;  // cols 0..127 sender (i), 128..255 receiver (j=row)
      const int k = (ks & 3) * 32 + q * 8;
      a[m][ks] = *(const bf16x8*)(enc + (size_t)(b * 16 + srow) * 128 + k);
    }
  }
  // pe1: 32x256 @ 256x256 (wave covers 64 cols)
  {
    f32x4 acc[2][4];
    reg_gemm<2, 4, 8>(a, fr + FR_PE_W1, w * 4, lane, acc);
    add_bias_act<2, 4, true>(acc, pe_b1, w * 64, lane);
    store_lds<2, 4, 512>(bufH, w * 64, lane, acc);
  }
  __syncthreads();
  // pe2: 32x256 @ 256x128 -> pi
  {
    f32x4 acc[2][2];
    lds_gemm<2, 2, 8>(bufH, fr + FR_PE_W2, w * 2, lane, acc);
    add_bias_act<2, 2, true>(acc, pe_b2, w * 32, lane);
    store_lds<2, 2, 256>(bufPi, w * 32, lane, acc);
  }
  __syncthreads();
  // ie1 + ia1: pi @ 128x128
  {
    f32x4 acc[2][2];
    lds_gemm<2, 2, 4>(bufPi, fr + FR_IE_W1, w * 2, lane, acc);
    add_bias_act<2, 2, true>(acc, ie_b1, w * 32, lane);
    store_lds<2, 2, 256>(bufH, w * 32, lane, acc);  // h_ie
    lds_gemm<2, 2, 4>(bufPi, fr + FR_IA_W1, w * 2, lane, acc);
    add_bias_act<2, 2, true>(acc, ia_b1, w * 32, lane);
    store_lds<2, 2, 256>(bufH + 32 * 128, w * 32, lane, acc);  // h_ia
  }
  __syncthreads();
  // ie2: h_ie @ 128x64 -> effect (regs)
  f32x4 eff[2][1];
  lds_gemm<2, 1, 4>(bufH, fr + FR_IE_W2, w, lane, eff);
  add_bias_act<2, 1, true>(eff, ie_b2, w * 16, lane);
  // ia2 (N=1, VALU): h_ia . ia_W2 -> att
  {
    const int row = t >> 3, s = t & 7;
    const int swz = (row & 7) << 4;
    const char* hia = (const char*)(bufH + 32 * 128) + row * 256;
    float sum = 0.f;
#pragma unroll
    for (int j = 0; j < 16; ++j) {
      int c = s * 16 + j;
      sum += bf2f(*(const ushort_t*)(hia + ((c * 2) ^ swz))) * ia_W2[c];
    }
    sum += __shfl_xor(sum, 1);
    sum += __shfl_xor(sum, 2);
    sum += __shfl_xor(sum, 4);
    if (s == 0) att[row] = sigmf(sum + ia_b2[0]);
  }
  __syncthreads();
  // total_effect[g] = sum_{j != i} effect[j] * att[j]
#pragma unroll
  for (int m = 0; m < 2; ++m) {
    const int im = (g0 + m) & 15;
    float part = 0.f;
#pragma unroll
    for (int k = 0; k < 4; ++k) {
      const int j = q * 4 + k;
      part += (j == im) ? 0.f : eff[m][0][k] * att[m * 16 + j];
    }
    part += __shfl_xor(part, 16);
    part += __shfl_xor(part, 32);
    if (q == 0) teff[(size_t)(g0 + m) * 64 + w * 16 + r] = f2bf(part);
  }
}

// ---------- kernel 3: final merge (fm) -> fp32 output ----------
__global__ __launch_bounds__(256, 2) void fm_kernel(
    const ushort_t* __restrict__ encf, const ushort_t* __restrict__ teff,
    const ushort_t* __restrict__ fr, const float* __restrict__ fm_b1,
    const float* __restrict__ fm_b2, float* __restrict__ out) {
  __shared__ ushort_t bufH[64 * 128];  // 16 KB
  const int t = threadIdx.x, lane = t & 63, w = t >> 6;
  const int rows0 = blockIdx.x * 64;
  const int r = lane & 15, q = lane >> 4;

  bf16x8 a[4][6];
#pragma unroll
  for (int m = 0; m < 4; ++m) {
    const size_t row = rows0 + m * 16 + r;
#pragma unroll
    for (int ks = 0; ks < 6; ++ks) {
      a[m][ks] = (ks < 4) ? *(const bf16x8*)(encf + row * 128 + ks * 32 + q * 8)
                          : *(const bf16x8*)(teff + row * 64 + (ks - 4) * 32 + q * 8);
    }
  }
  f32x4 acc[4][2];
  reg_gemm<4, 2, 6>(a, fr + FR_FM_W1, w * 2, lane, acc);
  add_bias_act<4, 2, true>(acc, fm_b1, w * 32, lane);
  store_lds<4, 2, 256>(bufH, w * 32, lane, acc);
  __syncthreads();
  lds_gemm<4, 2, 4>(bufH, fr + FR_FM_W2, w * 2, lane, acc);
  add_bias_act<4, 2, false>(acc, fm_b2, w * 32, lane);
  store_global_f32<4, 2>(out, rows0, 128, w * 32, lane, acc);
}

// ---------- launcher ----------
extern "C" void kernel_launch(void* const* d_in, const int* in_sizes, int n_in,
                              void* d_out, int out_size, void* d_ws, size_t ws_size,
                              hipStream_t stream) {
  (void)in_sizes; (void)n_in; (void)out_size; (void)ws_size;
  const float* lambda1 = (const float*)d_in[0];
  const float* actions = (const float*)d_in[1];

  ushort_t* ws = (ushort_t*)d_ws;
  ushort_t* encf = ws + OFF_ENCF;
  ushort_t* enc  = ws + OFF_ENC;
  ushort_t* teff = ws + OFF_TEFF;
  ushort_t* fr   = ws + OFF_FR;

  // weight prep (fragment repack, fp32 -> bf16)
  PrepArgs pa;
  const int src_idx[13] = {2, 4, 8, 10, 14, 12, 18, 20, 22, 24, 26, 30, 32};
  const int foff[13] = {FR_LE_W1, FR_LE_W2, FR_AE_W2, FR_AEF_W1, FR_AAT_W1, FR_AEF_W2,
                        FR_PE_W1, FR_PE_W2, FR_IE_W1, FR_IE_W2, FR_IA_W1, FR_FM_W1, FR_FM_W2};
  const int Ks[13] = {128, 128, 128, 192, 192, 128, 256, 256, 128, 128, 128, 192, 128};
  const int Ns[13] = {128, 128, 64, 128, 128, 128, 256, 128, 128, 64, 128, 128, 128};
  for (int i = 0; i < 13; ++i) {
    pa.d[i].src = (const float*)d_in[src_idx[i]];
    pa.d[i].dst = fr + foff[i];
    pa.d[i].K = Ks[i];
    pa.d[i].N = Ns[i];
  }
  prep_kernel<<<dim3(256, 13), 256, 0, stream>>>(pa);

  enc_kernel<<<512, 256, 0, stream>>>(
      lambda1, actions,
      (const float*)d_in[3], (const float*)d_in[5],              // le_b1, le_b2
      (const float*)d_in[6], (const float*)d_in[7],              // ae_W1, ae_b1
      (const float*)d_in[9],                                     // ae_b2
      (const float*)d_in[11], (const float*)d_in[13],            // aef_b1, aef_b2
      (const float*)d_in[15], (const float*)d_in[16],            // aat_b1, aat_W2
      (const float*)d_in[17],                                    // aat_b2
      fr, encf, enc);

  pair_kernel<<<16384, 256, 0, stream>>>(
      enc, fr,
      (const float*)d_in[19], (const float*)d_in[21],            // pe_b1, pe_b2
      (const float*)d_in[23], (const float*)d_in[25],            // ie_b1, ie_b2
      (const float*)d_in[27], (const float*)d_in[28],            // ia_b1, ia_W2
      (const float*)d_in[29],                                    // ia_b2
      teff);

  fm_kernel<<<512, 256, 0, stream>>>(encf, teff, fr,
                                     (const float*)d_in[31], (const float*)d_in[33],
                                     (float*)d_out);
}